// Round 3
// baseline (619.683 us; speedup 1.0000x reference)
//
#include <hip/hip_runtime.h>
#include <hip/hip_bf16.h>
#include <stdint.h>

// Problem constants: B=4, S=2048, IN=OUT=4096, R=16, SCALING=2.0
#define M_DIM 8192   // B*S
#define N_DIM 4096   // OUT
#define K_DIM 4096   // IN
#define R_DIM 16

#define PREP_BLOCKS 256     // 16 W-rows per block
#define CAST_BLOCKS 4096    // 2048 float4 per block (8 iters of 256)

typedef __attribute__((ext_vector_type(8))) short bf16x8;   // A/B frag (4 VGPRs)
typedef __attribute__((ext_vector_type(4))) float f32x4;    // C/D frag

__device__ __forceinline__ unsigned short f2bf(float f) {
  union { float f; unsigned int u; } v; v.f = f;
  unsigned int r = 0x7FFFu + ((v.u >> 16) & 1u);   // RNE
  return (unsigned short)((v.u + r) >> 16);
}

__device__ __forceinline__ void gload16(const unsigned short* g, unsigned short* l) {
  __builtin_amdgcn_global_load_lds(
      (const __attribute__((address_space(1))) void*)g,
      (__attribute__((address_space(3))) void*)l,
      16, 0, 0);
}

// ---- merged prep: blocks [0,256) = W' + scale;  blocks [256, 256+4096) = cast x ----
// LDS kept to ~17 KB so the cast blocks run ~8/CU (R2's 65 KB throttled them to 2/CU).
__global__ void __launch_bounds__(256) prep_kernel(
    const float4* __restrict__ x4, ushort4* __restrict__ xbf4,
    const float4* __restrict__ W4, const float4* __restrict__ Aw4,
    const float* __restrict__ Bw, const float* __restrict__ mag,
    ushort4* __restrict__ wbf4, float* __restrict__ scale) {
  const int tid = threadIdx.x;

  if (blockIdx.x >= PREP_BLOCKS) {
    // ---- cast x: fp32 -> bf16, 8 coalesced float4 per thread ----
    const int base = (blockIdx.x - PREP_BLOCKS) * 2048 + tid;
    #pragma unroll
    for (int u = 0; u < 8; ++u) {
      const int i = base + u * 256;
      float4 f = x4[i];
      ushort4 o;
      o.x = f2bf(f.x); o.y = f2bf(f.y); o.z = f2bf(f.z); o.w = f2bf(f.w);
      xbf4[i] = o;
    }
    return;
  }

  // ---- W' = W + 2*(B@A) for 16 rows; row norms; scale ----
  __shared__ float4 AwS[16 * 64];    // 16 KiB: 16 ranks x 256 cols (chunk)
  __shared__ float BoS[16 * 16];     // BoS[i*16+r] = Bw[o0+i][r]
  __shared__ float red[16];
  const int o0 = blockIdx.x * 16;
  const int g  = tid >> 6;           // wave -> handles rows 4g..4g+3
  const int j  = tid & 63;           // lane -> float4 column within chunk

  BoS[tid] = Bw[(o0 + (tid >> 4)) * R_DIM + (tid & 15)];

  float ss[4] = {0.f, 0.f, 0.f, 0.f};

  for (int c = 0; c < 16; ++c) {     // 16 chunks of 256 cols
    __syncthreads();                 // protect AwS reuse (and BoS on c==0)
    #pragma unroll
    for (int f = tid; f < 1024; f += 256)
      AwS[f] = Aw4[(size_t)(f >> 6) * 1024 + c * 64 + (f & 63)];
    __syncthreads();
    #pragma unroll
    for (int ii = 0; ii < 4; ++ii) {
      const int i = g * 4 + ii;      // row (wave-uniform)
      float4 w = W4[(size_t)(o0 + i) * 1024 + c * 64 + j];
      float4 acc = {0.f, 0.f, 0.f, 0.f};
      #pragma unroll
      for (int r = 0; r < R_DIM; ++r) {
        const float b = BoS[i * 16 + r];
        const float4 a = AwS[r * 64 + j];
        acc.x += b * a.x; acc.y += b * a.y; acc.z += b * a.z; acc.w += b * a.w;
      }
      float4 v;
      v.x = w.x + 2.f * acc.x; v.y = w.y + 2.f * acc.y;
      v.z = w.z + 2.f * acc.z; v.w = w.w + 2.f * acc.w;
      ss[ii] += v.x * v.x + v.y * v.y + v.z * v.z + v.w * v.w;
      ushort4 o;
      o.x = f2bf(v.x); o.y = f2bf(v.y); o.z = f2bf(v.z); o.w = f2bf(v.w);
      wbf4[(size_t)(o0 + i) * 1024 + c * 64 + j] = o;
    }
  }

  #pragma unroll
  for (int ii = 0; ii < 4; ++ii) {
    float s = ss[ii];
    #pragma unroll
    for (int off = 32; off > 0; off >>= 1) s += __shfl_down(s, off, 64);
    if (j == 0) red[g * 4 + ii] = s;
  }
  __syncthreads();
  if (tid < 16) scale[o0 + tid] = mag[o0 + tid] / sqrtf(red[tid]);
}

// ------------- GEMM: C[m,n] = scale[n] * sum_k A[m,k]*Bt[n,k] -------------
// 128x128 tile, BK=64: 32 MFMAs per barrier pair (2x the m97 structure) to
// amortize the vmcnt(0)+s_barrier drain. LDS 32 KiB total.
// Swizzle: LDS pos p (16B granule) of row r holds global chunk p ^ (r&7);
// fragment reads at (h*4+fq) ^ (fr&7) -> 2 lanes/granule per phase = free.
__global__ void __launch_bounds__(256)
dora_gemm(const unsigned short* __restrict__ A,   // [M,K] bf16
          const unsigned short* __restrict__ Bt,  // [N,K] bf16
          const float* __restrict__ scale,        // [N]
          float* __restrict__ C) {                // [M,N] fp32
  __shared__ __align__(16) unsigned short As[128 * 64];
  __shared__ __align__(16) unsigned short Bs[128 * 64];
  const int tid  = threadIdx.x;
  const int lane = tid & 63;
  const int wave = tid >> 6;
  const int bM = blockIdx.y * 128;
  const int bN = blockIdx.x * 128;

  // staging: wave w covers rows [32w, 32w+32) of both tiles, in 4 chunks of
  // 8 rows (1 KiB each). lane l -> row l>>3, fetches global chunk (l&7)^(row&7).
  const int sr = lane >> 3;                       // row within 8-row group
  const int sc = (((lane & 7) ^ sr) * 8);         // swizzled col (shorts)
  const unsigned short* pa = A  + (size_t)(bM + wave * 32 + sr) * K_DIM + sc;
  const unsigned short* pb = Bt + (size_t)(bN + wave * 32 + sr) * K_DIM + sc;
  unsigned short* lA = &As[wave * 32 * 64];
  unsigned short* lB = &Bs[wave * 32 * 64];

  const int fr = lane & 15;
  const int fq = lane >> 4;
  const int wM = (wave >> 1) * 64;
  const int wN = (wave & 1) * 64;

  f32x4 acc[4][4];
  #pragma unroll
  for (int i = 0; i < 4; ++i)
    #pragma unroll
    for (int jj = 0; jj < 4; ++jj) acc[i][jj] = (f32x4){0.f, 0.f, 0.f, 0.f};

  for (int k0 = 0; k0 < K_DIM; k0 += 64) {
    #pragma unroll
    for (int jj = 0; jj < 4; ++jj) {
      gload16(pa + (size_t)jj * 8 * K_DIM + k0, lA + jj * 512);
      gload16(pb + (size_t)jj * 8 * K_DIM + k0, lB + jj * 512);
    }
    __syncthreads();
    #pragma unroll
    for (int h = 0; h < 2; ++h) {
      bf16x8 aF[4], bF[4];
      #pragma unroll
      for (int mt = 0; mt < 4; ++mt)
        aF[mt] = *(const bf16x8*)&As[(wM + mt * 16 + fr) * 64 + (((h * 4 + fq) ^ (fr & 7)) * 8)];
      #pragma unroll
      for (int nt = 0; nt < 4; ++nt)
        bF[nt] = *(const bf16x8*)&Bs[(wN + nt * 16 + fr) * 64 + (((h * 4 + fq) ^ (fr & 7)) * 8)];
      #pragma unroll
      for (int mt = 0; mt < 4; ++mt)
        #pragma unroll
        for (int nt = 0; nt < 4; ++nt)
          acc[mt][nt] = __builtin_amdgcn_mfma_f32_16x16x32_bf16(aF[mt], bF[nt], acc[mt][nt], 0, 0, 0);
    }
    __syncthreads();
  }

  // epilogue: C/D layout col=lane&15, row=(lane>>4)*4+reg  [m89]
  float scv[4];
  #pragma unroll
  for (int nt = 0; nt < 4; ++nt) scv[nt] = scale[bN + wN + nt * 16 + fr];
  #pragma unroll
  for (int mt = 0; mt < 4; ++mt) {
    const int m0 = bM + wM + mt * 16 + fq * 4;
    #pragma unroll
    for (int nt = 0; nt < 4; ++nt) {
      const int n = bN + wN + nt * 16 + fr;
      #pragma unroll
      for (int r = 0; r < 4; ++r)
        C[(size_t)(m0 + r) * N_DIM + n] = acc[mt][nt][r] * scv[nt];
    }
  }
}

extern "C" void kernel_launch(void* const* d_in, const int* in_sizes, int n_in,
                              void* d_out, int out_size, void* d_ws, size_t ws_size,
                              hipStream_t stream) {
  const float* x   = (const float*)d_in[0];   // [4,2048,4096]
  const float* W   = (const float*)d_in[1];   // [4096,4096]
  const float* la  = (const float*)d_in[2];   // [16,4096]
  const float* lb  = (const float*)d_in[3];   // [4096,16]
  const float* mag = (const float*)d_in[4];   // [4096]
  float* out = (float*)d_out;

  // ws: x_bf16 (64 MiB) | w_bf16 (32 MiB) | scale (16 KiB)
  unsigned short* xbf = (unsigned short*)d_ws;
  unsigned short* wbf = (unsigned short*)((char*)d_ws + (size_t)M_DIM * K_DIM * 2);
  float* scale = (float*)((char*)d_ws + (size_t)M_DIM * K_DIM * 2 + (size_t)N_DIM * K_DIM * 2);

  prep_kernel<<<PREP_BLOCKS + CAST_BLOCKS, 256, 0, stream>>>(
      (const float4*)x, (ushort4*)xbf, (const float4*)W, (const float4*)la,
      lb, mag, (ushort4*)wbf, scale);
  dim3 grid(N_DIM / 128, M_DIM / 128);
  dora_gemm<<<grid, 256, 0, stream>>>(xbf, wbf, scale, out);
}

// Round 4
// 578.307 us; speedup vs baseline: 1.0715x; 1.0715x over previous
//
#include <hip/hip_runtime.h>
#include <hip/hip_bf16.h>
#include <stdint.h>

// Problem constants: B=4, S=2048, IN=OUT=4096, R=16, SCALING=2.0
#define M_DIM 8192   // B*S
#define N_DIM 4096   // OUT
#define K_DIM 4096   // IN
#define R_DIM 16

#define WPREP_BLOCKS 4096   // one W-row per block
#define CAST_BLOCKS  4096   // 2048 float4 per block

typedef __attribute__((ext_vector_type(8))) short bf16x8;   // A/B frag (4 VGPRs)
typedef __attribute__((ext_vector_type(4))) float f32x4;    // C/D frag

__device__ __forceinline__ unsigned short f2bf(float f) {
  union { float f; unsigned int u; } v; v.f = f;
  unsigned int r = 0x7FFFu + ((v.u >> 16) & 1u);   // RNE
  return (unsigned short)((v.u + r) >> 16);
}

__device__ __forceinline__ void gload16(const unsigned short* g, unsigned short* l) {
  __builtin_amdgcn_global_load_lds(
      (const __attribute__((address_space(1))) void*)g,
      (__attribute__((address_space(3))) void*)l,
      16, 0, 0);
}

// ---- merged prep, no-LDS / no-barrier structure ----
// blocks [0, 4096): W' = W + 2*(B@A) for row o=blockIdx; row norm; scale.
//   thread t handles float4-cols {t, 256+t, 512+t, 768+t} (coalesced).
//   Aw (256 KB) served from L1/L2; Bw row -> scalar regs (uniform).
// blocks [4096, 8192): cast x fp32->bf16, 8 coalesced float4 per thread.
__global__ void __launch_bounds__(256) prep_kernel(
    const float4* __restrict__ x4, ushort4* __restrict__ xbf4,
    const float4* __restrict__ W4, const float4* __restrict__ Aw4,
    const float* __restrict__ Bw, const float* __restrict__ mag,
    ushort4* __restrict__ wbf4, float* __restrict__ scale) {
  const int tid = threadIdx.x;

  if (blockIdx.x >= WPREP_BLOCKS) {
    const int base = (blockIdx.x - WPREP_BLOCKS) * 2048 + tid;
    #pragma unroll
    for (int u = 0; u < 8; ++u) {
      const int i = base + u * 256;
      float4 f = x4[i];
      ushort4 o;
      o.x = f2bf(f.x); o.y = f2bf(f.y); o.z = f2bf(f.z); o.w = f2bf(f.w);
      xbf4[i] = o;
    }
    return;
  }

  const int o = blockIdx.x;
  float Bo[R_DIM];
  #pragma unroll
  for (int r = 0; r < R_DIM; ++r) Bo[r] = Bw[o * R_DIM + r] * 2.0f;  // fold SCALING

  float ss = 0.f;
  #pragma unroll
  for (int g = 0; g < 4; ++g) {
    const int c = g * 256 + tid;                  // float4 column, coalesced
    float4 v = W4[(size_t)o * 1024 + c];
    #pragma unroll
    for (int r = 0; r < R_DIM; ++r) {
      const float4 a = Aw4[(size_t)r * 1024 + c];
      const float b = Bo[r];
      v.x += b * a.x; v.y += b * a.y; v.z += b * a.z; v.w += b * a.w;
    }
    ss += v.x * v.x + v.y * v.y + v.z * v.z + v.w * v.w;
    ushort4 ov;
    ov.x = f2bf(v.x); ov.y = f2bf(v.y); ov.z = f2bf(v.z); ov.w = f2bf(v.w);
    wbf4[(size_t)o * 1024 + c] = ov;
  }

  __shared__ float red[4];
  #pragma unroll
  for (int off = 32; off > 0; off >>= 1) ss += __shfl_down(ss, off, 64);
  if ((tid & 63) == 0) red[tid >> 6] = ss;
  __syncthreads();
  if (tid == 0)
    scale[o] = mag[o] / sqrtf(red[0] + red[1] + red[2] + red[3]);
}

// ------------- GEMM: C[m,n] = scale[n] * sum_k A[m,k]*Bt[n,k] -------------
// 128x128 tile, BK=64: 32 MFMAs per barrier pair. LDS 32 KiB total.
// Swizzle: LDS pos p (16B granule) of row r holds global chunk p ^ (r&7);
// fragment reads at (h*4+fq) ^ (fr&7) -> conflict-free (verified R2/R3: 0).
__global__ void __launch_bounds__(256)
dora_gemm(const unsigned short* __restrict__ A,   // [M,K] bf16
          const unsigned short* __restrict__ Bt,  // [N,K] bf16
          const float* __restrict__ scale,        // [N]
          float* __restrict__ C) {                // [M,N] fp32
  __shared__ __align__(16) unsigned short As[128 * 64];
  __shared__ __align__(16) unsigned short Bs[128 * 64];
  const int tid  = threadIdx.x;
  const int lane = tid & 63;
  const int wave = tid >> 6;
  const int bM = blockIdx.y * 128;
  const int bN = blockIdx.x * 128;

  const int sr = lane >> 3;                       // row within 8-row group
  const int sc = (((lane & 7) ^ sr) * 8);         // swizzled col (shorts)
  const unsigned short* pa = A  + (size_t)(bM + wave * 32 + sr) * K_DIM + sc;
  const unsigned short* pb = Bt + (size_t)(bN + wave * 32 + sr) * K_DIM + sc;
  unsigned short* lA = &As[wave * 32 * 64];
  unsigned short* lB = &Bs[wave * 32 * 64];

  const int fr = lane & 15;
  const int fq = lane >> 4;
  const int wM = (wave >> 1) * 64;
  const int wN = (wave & 1) * 64;

  f32x4 acc[4][4];
  #pragma unroll
  for (int i = 0; i < 4; ++i)
    #pragma unroll
    for (int jj = 0; jj < 4; ++jj) acc[i][jj] = (f32x4){0.f, 0.f, 0.f, 0.f};

  for (int k0 = 0; k0 < K_DIM; k0 += 64) {
    #pragma unroll
    for (int jj = 0; jj < 4; ++jj) {
      gload16(pa + (size_t)jj * 8 * K_DIM + k0, lA + jj * 512);
      gload16(pb + (size_t)jj * 8 * K_DIM + k0, lB + jj * 512);
    }
    __syncthreads();
    #pragma unroll
    for (int h = 0; h < 2; ++h) {
      bf16x8 aF[4], bF[4];
      #pragma unroll
      for (int mt = 0; mt < 4; ++mt)
        aF[mt] = *(const bf16x8*)&As[(wM + mt * 16 + fr) * 64 + (((h * 4 + fq) ^ (fr & 7)) * 8)];
      #pragma unroll
      for (int nt = 0; nt < 4; ++nt)
        bF[nt] = *(const bf16x8*)&Bs[(wN + nt * 16 + fr) * 64 + (((h * 4 + fq) ^ (fr & 7)) * 8)];
      #pragma unroll
      for (int mt = 0; mt < 4; ++mt)
        #pragma unroll
        for (int nt = 0; nt < 4; ++nt)
          acc[mt][nt] = __builtin_amdgcn_mfma_f32_16x16x32_bf16(aF[mt], bF[nt], acc[mt][nt], 0, 0, 0);
    }
    __syncthreads();
  }

  // epilogue: C/D layout col=lane&15, row=(lane>>4)*4+reg  [m89]
  float scv[4];
  #pragma unroll
  for (int nt = 0; nt < 4; ++nt) scv[nt] = scale[bN + wN + nt * 16 + fr];
  #pragma unroll
  for (int mt = 0; mt < 4; ++mt) {
    const int m0 = bM + wM + mt * 16 + fq * 4;
    #pragma unroll
    for (int nt = 0; nt < 4; ++nt) {
      const int n = bN + wN + nt * 16 + fr;
      #pragma unroll
      for (int r = 0; r < 4; ++r)
        C[(size_t)(m0 + r) * N_DIM + n] = acc[mt][nt][r] * scv[nt];
    }
  }
}

extern "C" void kernel_launch(void* const* d_in, const int* in_sizes, int n_in,
                              void* d_out, int out_size, void* d_ws, size_t ws_size,
                              hipStream_t stream) {
  const float* x   = (const float*)d_in[0];   // [4,2048,4096]
  const float* W   = (const float*)d_in[1];   // [4096,4096]
  const float* la  = (const float*)d_in[2];   // [16,4096]
  const float* lb  = (const float*)d_in[3];   // [4096,16]
  const float* mag = (const float*)d_in[4];   // [4096]
  float* out = (float*)d_out;

  // ws: x_bf16 (64 MiB) | w_bf16 (32 MiB) | scale (16 KiB)
  unsigned short* xbf = (unsigned short*)d_ws;
  unsigned short* wbf = (unsigned short*)((char*)d_ws + (size_t)M_DIM * K_DIM * 2);
  float* scale = (float*)((char*)d_ws + (size_t)M_DIM * K_DIM * 2 + (size_t)N_DIM * K_DIM * 2);

  prep_kernel<<<WPREP_BLOCKS + CAST_BLOCKS, 256, 0, stream>>>(
      (const float4*)x, (ushort4*)xbf, (const float4*)W, (const float4*)la,
      lb, mag, (ushort4*)wbf, scale);
  dim3 grid(N_DIM / 128, M_DIM / 128);
  dora_gemm<<<grid, 256, 0, stream>>>(xbf, wbf, scale, out);
}